// Round 12
// baseline (387.153 us; speedup 1.0000x reference)
//
#include <hip/hip_runtime.h>
#include <hip/hip_bf16.h>

#define NEG_SLOPE 0.1f
#define D1 128
#define D2 256

// bucket = 128 consecutive node ids (shift 7). Edge blocks = 4096 edges.
#define BSH 7
#define NPB 128
#define EPB 4096
#define MAXBUK 1024   // LDS arrays sized for NBUK <= 1024 (N <= 131072)

__device__ __forceinline__ float leaky(float x) { return x >= 0.f ? x : NEG_SLOPE * x; }

__device__ __forceinline__ unsigned short f2bf(float x) {
    union { float f; unsigned int u; } v; v.f = x;
    unsigned int r = (v.u + 0x7FFFu + ((v.u >> 16) & 1u)) >> 16;   // RNE
    return (unsigned short)r;
}

__device__ __forceinline__ unsigned int pk2bf(float a, float b) {
    return (unsigned int)f2bf(a) | ((unsigned int)f2bf(b) << 16);
}

// scanned-table read with the block-partials fixup folded in
__device__ __forceinline__ int ts_g(const int* __restrict__ TS,
                                    const int* __restrict__ partials, int idx) {
    return TS[idx] + partials[idx >> 11];
}

// ---- pass A: per-(block,bucket) histograms for col-keys and row-keys ----
__global__ __launch_bounds__(256) void k_hist(const int* __restrict__ row,
                                              const int* __restrict__ col,
                                              int* __restrict__ T,
                                              int E, int NBLK, int NBUK)
{
    __shared__ int hc[MAXBUK], hr[MAXBUK];
    for (int b = threadIdx.x; b < NBUK; b += 256) { hc[b] = 0; hr[b] = 0; }
    __syncthreads();
    int base = blockIdx.x * EPB;
#pragma unroll 8
    for (int i = 0; i < EPB / 256; i++) {
        int e = base + i * 256 + threadIdx.x;
        if (e < E) {
            atomicAdd(&hc[col[e] >> BSH], 1);
            atomicAdd(&hr[row[e] >> BSH], 1);
        }
    }
    __syncthreads();
    int NT = NBUK * NBLK;
    for (int b = threadIdx.x; b < NBUK; b += 256) {
        T[b * NBLK + blockIdx.x]      = hc[b];
        T[NT + b * NBLK + blockIdx.x] = hr[b];
    }
}

// ---- exclusive scan: local pass + partials pass (fixup folded into readers) ----
__global__ __launch_bounds__(256) void k_scan_local(const int* __restrict__ in, int* __restrict__ out,
                                                    int* __restrict__ partials, int n)
{
    __shared__ int s[256];
    int base = blockIdx.x * 2048 + threadIdx.x * 8;
    int v[8]; int sum = 0;
#pragma unroll
    for (int i = 0; i < 8; i++) { v[i] = (base + i < n) ? in[base + i] : 0; sum += v[i]; }
    s[threadIdx.x] = sum;
    __syncthreads();
    for (int off = 1; off < 256; off <<= 1) {
        int t = (threadIdx.x >= off) ? s[threadIdx.x - off] : 0;
        __syncthreads();
        s[threadIdx.x] += t;
        __syncthreads();
    }
    int excl = s[threadIdx.x] - sum;
#pragma unroll
    for (int i = 0; i < 8; i++) { if (base + i < n) { out[base + i] = excl; excl += v[i]; } }
    if (threadIdx.x == 255) partials[blockIdx.x] = s[255];
}

// block 0: parallel exclusive scan of up to 1024 block partials.
// blocks 1..32: weight pre-convert to fragment-layout bf16:
//   w2f[((k>>3)*256 + m)*8 + (k&7)] = bf16(w2[m][k])   (m<256, k<128)
//   w3f[((k>>3)*128 + m)*8 + (k&7)] = bf16(w3[m][k])   (m<128, k<256)
__global__ __launch_bounds__(1024) void k_scan_cvt(int* __restrict__ partials, int nb,
                                                   const float* __restrict__ w2,
                                                   const float* __restrict__ w3,
                                                   unsigned short* __restrict__ w2f,
                                                   unsigned short* __restrict__ w3f)
{
    int t = threadIdx.x;
    if (blockIdx.x == 0) {
        __shared__ int s[1024];
        int v = (t < nb) ? partials[t] : 0;
        s[t] = v;
        __syncthreads();
        for (int off = 1; off < 1024; off <<= 1) {
            int u = (t >= off) ? s[t - off] : 0;
            __syncthreads();
            s[t] += u;
            __syncthreads();
        }
        if (t < nb) partials[t] = s[t] - v;
    } else {
        int i = (blockIdx.x - 1) * 1024 + t;    // 0 .. 32767 (both tables 32768 elems)
        {
            int m = i >> 7, k = i & 127;
            w2f[(((k >> 3) * 256 + m) << 3) + (k & 7)] = f2bf(w2[i]);
        }
        {
            int m = i >> 8, k = i & 255;
            w3f[(((k >> 3) * 128 + m) << 3) + (k & 7)] = f2bf(w3[i]);
        }
    }
}

// ---- pass B: scatter edges to col-bucket regions (X) and row-bucket regions (Y) ----
// X entry: .x = (c_local<<25) | r   (needs N < 2^25), .y = val bits
// Y entry: .x = r_local, .y = |val| bits
__global__ __launch_bounds__(256) void k_scat(const int* __restrict__ row,
                                              const int* __restrict__ col,
                                              const float* __restrict__ val,
                                              const int* __restrict__ TS,
                                              const int* __restrict__ partials,
                                              int2* __restrict__ X, int2* __restrict__ Y,
                                              int E, int NBLK, int NBUK)
{
    __shared__ int oc[MAXBUK], orw[MAXBUK];
    int NT = NBUK * NBLK;
    for (int b = threadIdx.x; b < NBUK; b += 256) {
        oc[b]  = ts_g(TS, partials, b * NBLK + blockIdx.x);
        orw[b] = ts_g(TS, partials, NT + b * NBLK + blockIdx.x);
    }
    __syncthreads();
    int base = blockIdx.x * EPB;
#pragma unroll 8
    for (int i = 0; i < EPB / 256; i++) {
        int e = base + i * 256 + threadIdx.x;
        if (e < E) {
            int r = row[e], c = col[e];
            float v = val[e];
            int pc = atomicAdd(&oc[c >> BSH], 1);
            X[pc] = make_int2(((c & (NPB - 1)) << 25) | r, __float_as_int(v));
            int pr = atomicAdd(&orw[r >> BSH], 1);
            Y[pr - E] = make_int2(r & (NPB - 1), __float_as_int(fabsf(v)));
        }
    }
}

// ---- pass C (row): per-row-bucket reduction -> dinv, pv_self ----
__global__ __launch_bounds__(256) void k_rowstats(const int2* __restrict__ Y,
                                                  const int* __restrict__ TS,
                                                  const int* __restrict__ partials,
                                                  float* __restrict__ dinv,
                                                  float* __restrict__ pv_self,
                                                  int N, int E, int NBLK, int NBUK)
{
    __shared__ float fs[NPB];
    __shared__ int   cn[NPB];
    int t = threadIdx.x;
    if (t < NPB) { fs[t] = 0.f; cn[t] = 0; }
    __syncthreads();
    int NT = NBUK * NBLK;
    int buk = blockIdx.x;
    int s = ts_g(TS, partials, NT + buk * NBLK);
    int e = (buk == NBUK - 1) ? 2 * E : ts_g(TS, partials, NT + (buk + 1) * NBLK);
    for (int j = s + t; j < e; j += 256) {
        int2 y = Y[j - E];
        atomicAdd(&fs[y.x], __int_as_float(y.y));
        atomicAdd(&cn[y.x], 1);
    }
    __syncthreads();
    if (t < NPB) {
        int node = buk * NPB + t;
        if (node < N) {
            float as = fs[t];
            float c  = (float)cn[t];
            float am = as / fmaxf(c, 1.f);
            float deg = as + am;
            float di = deg > 0.f ? rsqrtf(deg) : 0.f;
            dinv[node]    = di;
            pv_self[node] = am * di * di;
        }
    }
}

// ---- pass C (col): per-col-bucket node ranking -> col_ptr, srt_rp (r,pv), x1 ----
__global__ __launch_bounds__(256) void k_colfinal(const int2* __restrict__ X,
                                                  const int* __restrict__ TS,
                                                  const int* __restrict__ partials,
                                                  const float* __restrict__ dinv,
                                                  const float* __restrict__ pv_self,
                                                  int* __restrict__ col_ptr,
                                                  int2* __restrict__ srt_rp,
                                                  float* __restrict__ x1,
                                                  int N, int E, int NBLK, int NBUK)
{
    __shared__ int   hist[NPB];
    __shared__ int   tmp[NPB];
    __shared__ int   rb[NPB];
    __shared__ float xs[NPB];
    __shared__ float dl[NPB];
    int t = threadIdx.x;
    int buk = blockIdx.x;
    int node = buk * NPB + t;
    if (t < NPB) {
        hist[t] = 0; xs[t] = 0.f;
        dl[t] = (node < N) ? dinv[node] : 0.f;
    }
    __syncthreads();
    int s  = ts_g(TS, partials, buk * NBLK);
    int e2 = (buk == NBUK - 1) ? E : ts_g(TS, partials, (buk + 1) * NBLK);
    for (int j = s + t; j < e2; j += 256) {
        unsigned xw = (unsigned)X[j].x;
        atomicAdd(&hist[xw >> 25], 1);
    }
    __syncthreads();
    if (t < NPB) tmp[t] = hist[t];
    __syncthreads();
    for (int off = 1; off < NPB; off <<= 1) {
        int u = (t >= off && t < NPB) ? tmp[t - off] : 0;
        __syncthreads();
        if (t < NPB) tmp[t] += u;
        __syncthreads();
    }
    if (t < NPB) {
        int excl = tmp[t] - hist[t];
        rb[t] = s + excl;
        if (node < N) col_ptr[node] = s + excl;
    }
    if (buk == NBUK - 1 && t == 0) col_ptr[N] = E;
    __syncthreads();
    for (int j = s + t; j < e2; j += 256) {
        int2 xx = X[j];
        unsigned xw = (unsigned)xx.x;
        int cl = xw >> 25;
        int r  = (int)(xw & 0x1FFFFFFu);
        float p = __int_as_float(xx.y) * dinv[r] * dl[cl];
        int pos = atomicAdd(&rb[cl], 1);
        srt_rp[pos] = make_int2(r, __float_as_int(p));
        atomicAdd(&xs[cl], p);
    }
    __syncthreads();
    if (t < NPB && node < N) x1[node] = pv_self[node] + xs[t];
}

// ---- conv2 propagate, broadcast form: one wave per node, 2 dims per lane.
// Node-range form [n0, nEnd) for split launches (attribution + load split).
__global__ __launch_bounds__(256) void k_prop2b(const int* __restrict__ col_ptr,
                                                const int2* __restrict__ srt_rp,
                                                const float* __restrict__ pv_self,
                                                const float* __restrict__ x1,
                                                const float* __restrict__ w1,
                                                const float* __restrict__ b1,
                                                unsigned int* __restrict__ p2b,
                                                int n0, int nEnd)
{
    int node = n0 + blockIdx.x * 4 + (threadIdx.x >> 6);
    int lane = threadIdx.x & 63;
    if (node >= nEnd) return;

    float2 w = *(const float2*)&w1[lane * 2];
    float2 b = *(const float2*)&b1[lane * 2];
    float ps  = pv_self[node];
    float x1n = x1[node];
    float acc0 = ps * leaky(fmaf(x1n, w.x, b.x));
    float acc1 = ps * leaky(fmaf(x1n, w.y, b.y));

    int s = col_ptr[node], e = col_ptr[node + 1];
    for (int base = s; base < e; base += 64) {
        int mc = min(64, e - base);
        float p = 0.f, sv = 0.f;
        if (lane < mc) {
            int2 rp = srt_rp[base + lane];
            p  = __int_as_float(rp.y);
            sv = x1[rp.x];
        }
        int k = 0;
        for (; k + 3 < mc; k += 4) {
            float pk0 = __shfl(p, k, 64),     sk0 = __shfl(sv, k, 64);
            float pk1 = __shfl(p, k + 1, 64), sk1 = __shfl(sv, k + 1, 64);
            float pk2 = __shfl(p, k + 2, 64), sk2 = __shfl(sv, k + 2, 64);
            float pk3 = __shfl(p, k + 3, 64), sk3 = __shfl(sv, k + 3, 64);
            acc0 += pk0 * leaky(fmaf(sk0, w.x, b.x));
            acc1 += pk0 * leaky(fmaf(sk0, w.y, b.y));
            acc0 += pk1 * leaky(fmaf(sk1, w.x, b.x));
            acc1 += pk1 * leaky(fmaf(sk1, w.y, b.y));
            acc0 += pk2 * leaky(fmaf(sk2, w.x, b.x));
            acc1 += pk2 * leaky(fmaf(sk2, w.y, b.y));
            acc0 += pk3 * leaky(fmaf(sk3, w.x, b.x));
            acc1 += pk3 * leaky(fmaf(sk3, w.y, b.y));
        }
        for (; k < mc; ++k) {
            float pk = __shfl(p, k, 64);
            float sk = __shfl(sv, k, 64);
            acc0 += pk * leaky(fmaf(sk, w.x, b.x));
            acc1 += pk * leaky(fmaf(sk, w.y, b.y));
        }
    }

    p2b[(size_t)node * 64 + lane] = pk2bf(acc0, acc1);
}

// ---- conv3 gather propagate over bf16 z, one wave per node, 4-edge unroll.
// Node-range form [n0, nEnd) for split launches.
__global__ __launch_bounds__(256) void k_prop3_bf16(const int* __restrict__ col_ptr,
                                                    const int2* __restrict__ srt_rp,
                                                    const float* __restrict__ pv_self,
                                                    const unsigned int* __restrict__ zb,
                                                    const float* __restrict__ bias3,
                                                    float* __restrict__ out,
                                                    int n0, int nEnd)
{
    int node = n0 + blockIdx.x * 4 + (threadIdx.x >> 6);
    int lane = threadIdx.x & 63;
    if (node >= nEnd) return;

    unsigned int us = zb[(size_t)node * 64 + lane];
    float ps = pv_self[node];
    float acc0 = ps * __uint_as_float(us << 16);
    float acc1 = ps * __uint_as_float(us & 0xFFFF0000u);

    int j = col_ptr[node], e = col_ptr[node + 1];
    for (; j + 3 < e; j += 4) {
        int2 rp0 = srt_rp[j];
        int2 rp1 = srt_rp[j + 1];
        int2 rp2 = srt_rp[j + 2];
        int2 rp3 = srt_rp[j + 3];
        unsigned int u0 = zb[(size_t)rp0.x * 64 + lane];
        unsigned int u1 = zb[(size_t)rp1.x * 64 + lane];
        unsigned int u2 = zb[(size_t)rp2.x * 64 + lane];
        unsigned int u3 = zb[(size_t)rp3.x * 64 + lane];
        float p0 = __int_as_float(rp0.y);
        float p1 = __int_as_float(rp1.y);
        float p2 = __int_as_float(rp2.y);
        float p3 = __int_as_float(rp3.y);
        acc0 += p0 * __uint_as_float(u0 << 16);
        acc1 += p0 * __uint_as_float(u0 & 0xFFFF0000u);
        acc0 += p1 * __uint_as_float(u1 << 16);
        acc1 += p1 * __uint_as_float(u1 & 0xFFFF0000u);
        acc0 += p2 * __uint_as_float(u2 << 16);
        acc1 += p2 * __uint_as_float(u2 & 0xFFFF0000u);
        acc0 += p3 * __uint_as_float(u3 << 16);
        acc1 += p3 * __uint_as_float(u3 & 0xFFFF0000u);
    }
    for (; j < e; ++j) {
        int2 rp = srt_rp[j];
        unsigned int u = zb[(size_t)rp.x * 64 + lane];
        float p = __int_as_float(rp.y);
        acc0 += p * __uint_as_float(u << 16);
        acc1 += p * __uint_as_float(u & 0xFFFF0000u);
    }

    float2 b = *(const float2*)&bias3[lane * 2];
    float2 o = make_float2(leaky(acc0 + b.x), leaky(acc1 + b.y));
    *(float2*)&out[(size_t)node * D1 + lane * 2] = o;
}

// ---- fused MFMA GEMM chain v4: full fragment preload (ILP over TLP) ----
__global__ __launch_bounds__(256, 2) void k_gemm_fused4(const unsigned int* __restrict__ p2b,
                                                        const unsigned short* __restrict__ w2f,
                                                        const float* __restrict__ b2,
                                                        const float* __restrict__ bias2,
                                                        const unsigned short* __restrict__ w3f,
                                                        const float* __restrict__ b3,
                                                        const float* __restrict__ x1,
                                                        unsigned short* __restrict__ zb,
                                                        int N)
{
    typedef __attribute__((ext_vector_type(8))) short short8v;
    typedef __attribute__((ext_vector_type(4))) float f32x4;

    __shared__ unsigned short H[32 * 64 * 8];   // H^T tile, [w2col/8][node][8], 32 KB

    const int t = threadIdx.x;
    const int n_base = blockIdx.x * 64;
    const int l  = t & 63, wid = t >> 6;
    const int lr = l & 15, lk = l >> 4;

    // ---- phase 1 preload: all 16 w2 frags + all 16 p2 frags ----
    short8v a1[4][4], p1[4][4];
#pragma unroll
    for (int ks = 0; ks < 4; ks++) {
        const int k0 = ks * 32;
#pragma unroll
        for (int i = 0; i < 4; i++)
            a1[ks][i] = *(const short8v*)&w2f[((((k0 >> 3) + lk) * 256) + wid * 64 + i * 16 + lr) * 8];
#pragma unroll
        for (int j = 0; j < 4; j++) {
            int node = n_base + j * 16 + lr;
            if (node >= N) node = N - 1;
            p1[ks][j] = *(const short8v*)&p2b[(size_t)node * 64 + (k0 >> 1) + lk * 4];
        }
    }

    // ---- phase 1 MFMA burst: wave owns w2cols [wid*64, wid*64+64) ----
    f32x4 acc1[4][4] = {};
#pragma unroll
    for (int ks = 0; ks < 4; ks++)
#pragma unroll
        for (int i = 0; i < 4; i++)
#pragma unroll
            for (int j = 0; j < 4; j++)
                acc1[i][j] = __builtin_amdgcn_mfma_f32_16x16x32_bf16(a1[ks][i], p1[ks][j], acc1[i][j], 0, 0, 0);

    // ---- phase 2 weight preload (overlaps epilogue 1; a1/p1 regs are dead) ----
    short8v a2[8][2];
#pragma unroll
    for (int ks = 0; ks < 8; ks++) {
        const int k0 = ks * 32;
#pragma unroll
        for (int i = 0; i < 2; i++)
            a2[ks][i] = *(const short8v*)&w3f[((((k0 >> 3) + lk) * 128) + wid * 32 + i * 16 + lr) * 8];
    }

    // ---- epilogue 1 -> H (packed b64 writes; k-quads are lane-local) ----
    {
        float xv[4];
#pragma unroll
        for (int j = 0; j < 4; j++) {
            int node = n_base + j * 16 + lr;
            xv[j] = (node < N) ? x1[node] : 0.f;
        }
#pragma unroll
        for (int i = 0; i < 4; i++) {
            const int c0 = wid * 64 + i * 16 + lk * 4;   // 4 consecutive w2cols
            float4 bq  = *(const float4*)&b2[c0];
            float4 biq = *(const float4*)&bias2[c0];
            const int kblk = wid * 8 + i * 2 + (lk >> 1);
#pragma unroll
            for (int j = 0; j < 4; j++) {
                float v0 = leaky(acc1[i][j][0] + xv[j] * bq.x + biq.x);
                float v1 = leaky(acc1[i][j][1] + xv[j] * bq.y + biq.y);
                float v2 = leaky(acc1[i][j][2] + xv[j] * bq.z + biq.z);
                float v3 = leaky(acc1[i][j][3] + xv[j] * bq.w + biq.w);
                uint2 pk = make_uint2(pk2bf(v0, v1), pk2bf(v2, v3));
                *(uint2*)&H[(kblk * 64 + j * 16 + lr) * 8 + (lk & 1) * 4] = pk;
            }
        }
    }
    __syncthreads();

    // ---- phase 2: wave owns w3cols [wid*32, wid*32+32); H from LDS ----
    f32x4 acc2[2][4] = {};
#pragma unroll
    for (int ks = 0; ks < 8; ks++) {
        const int k0 = ks * 32;
        short8v bf[4];
#pragma unroll
        for (int j = 0; j < 4; j++)
            bf[j] = *(const short8v*)&H[(((k0 >> 3) + lk) * 64 + j * 16 + lr) * 8];
#pragma unroll
        for (int i = 0; i < 2; i++)
#pragma unroll
            for (int j = 0; j < 4; j++)
                acc2[i][j] = __builtin_amdgcn_mfma_f32_16x16x32_bf16(a2[ks][i], bf[j], acc2[i][j], 0, 0, 0);
    }

    // ---- epilogue 2 -> zb (packed ushort4 stores) ----
#pragma unroll
    for (int i = 0; i < 2; i++) {
        const int m0 = wid * 32 + i * 16 + lk * 4;   // 4 consecutive z-cols
        float4 bq = *(const float4*)&b3[m0];
#pragma unroll
        for (int j = 0; j < 4; j++) {
            int node = n_base + j * 16 + lr;
            if (node < N) {
                ushort4 s4;
                s4.x = f2bf(acc2[i][j][0] + bq.x);
                s4.y = f2bf(acc2[i][j][1] + bq.y);
                s4.z = f2bf(acc2[i][j][2] + bq.z);
                s4.w = f2bf(acc2[i][j][3] + bq.w);
                *(ushort4*)&zb[(size_t)node * D1 + m0] = s4;
            }
        }
    }
}

extern "C" void kernel_launch(void* const* d_in, const int* in_sizes, int n_in,
                              void* d_out, int out_size, void* d_ws, size_t ws_size,
                              hipStream_t stream)
{
    const int* ei       = (const int*)d_in[0];     // (2,E) int32
    const float* val    = (const float*)d_in[1];   // (E,)
    const float* w1     = (const float*)d_in[3];   // (128,1)
    const float* b1     = (const float*)d_in[4];   // (128,)
    const float* w2     = (const float*)d_in[5];   // (256,128)
    const float* b2     = (const float*)d_in[6];   // (256,)
    const float* bias2  = (const float*)d_in[7];   // (256,)
    const float* w3     = (const float*)d_in[8];   // (128,256)
    const float* b3     = (const float*)d_in[9];   // (128,)
    const float* bias3  = (const float*)d_in[10];  // (128,)
    float* out = (float*)d_out;

    const int E = in_sizes[1];
    const int N = out_size / D1;
    const int* row = ei;
    const int* col = ei + E;

    const int NBLK = (E + EPB - 1) / EPB;          // edge blocks (391 @ E=1.6M)
    const int NBUK = (N + NPB - 1) >> BSH;         // node buckets (782 @ N=100K)
    const int NT   = NBUK * NBLK;

    // workspace layout
    float* dinv    = (float*)d_ws;                                   // N
    float* pv_self = dinv + N;                                       // N
    float* x1      = pv_self + N;                                    // N
    int*   col_ptr = (int*)(x1 + N);                                 // N+8
    int*   partials= col_ptr + N + 8;                                // 1024
    int2*  srt_rp  = (int2*)(partials + 1024);                       // E int2
    unsigned int* p2b = (unsigned int*)(srt_rp + (size_t)E);         // N*64 uints (bf16 p2)
    int*   TS      = (int*)(p2b + (size_t)N * 64);                   // 2*NT scanned table
    int*   T       = TS + (size_t)2 * NT;                            // 2*NT raw histograms
    int2*  Y       = (int2*)(T + (size_t)2 * NT);                    // E (row-bucketed edges)
    unsigned short* w2f = (unsigned short*)(Y + (size_t)E);          // 32768 bf16 (frag layout)
    unsigned short* w3f = w2f + 32768;                               // 32768 bf16 (frag layout)
    unsigned short* zb  = w3f + 32768;                               // N*128 bf16 z (de-aliased)
    // alias:
    int2* X = (int2*)p2b;                    // E entries; dead before k_prop2b writes p2b (E*8 <= N*256)

    const int B = 256;
    const int n2 = 2 * NT;
    const int scan_blocks = (n2 + 2047) / 2048;    // 299 @ default sizes (<= 1024)

    // bucket-sort pipeline: LDS atomics only, zero global atomics, no memsets
    k_hist<<<NBLK, B, 0, stream>>>(row, col, T, E, NBLK, NBUK);
    k_scan_local<<<scan_blocks, 256, 0, stream>>>(T, TS, partials, n2);
    k_scan_cvt<<<33, 1024, 0, stream>>>(partials, scan_blocks, w2, w3, w2f, w3f);
    k_scat<<<NBLK, B, 0, stream>>>(row, col, val, TS, partials, X, Y, E, NBLK, NBUK);
    k_rowstats<<<NBUK, B, 0, stream>>>(Y, TS, partials, dinv, pv_self, N, E, NBLK, NBUK);
    k_colfinal<<<NBUK, B, 0, stream>>>(X, TS, partials, dinv, pv_self, col_ptr, srt_rp, x1, N, E, NBLK, NBUK);

    // conv2 propagate -> bf16 p2 (2 node-range halves), then fused MFMA chain
    {
        int half = (N + 1) / 2;
        k_prop2b<<<(half + 3) / 4, 256, 0, stream>>>(col_ptr, srt_rp, pv_self, x1, w1, b1, p2b, 0, half);
        k_prop2b<<<((N - half) + 3) / 4, 256, 0, stream>>>(col_ptr, srt_rp, pv_self, x1, w1, b1, p2b, half, N);
    }
    k_gemm_fused4<<<(N + 63) / 64, 256, 0, stream>>>(p2b, w2f, b2, bias2, w3f, b3, x1, zb, N);

    // conv3 gather propagate + fused bias3/leaky (4 node-range quarters)
    {
        int q = (N + 3) / 4;
        for (int i = 0; i < 4; i++) {
            int a = i * q;
            int bnd = min(N, a + q);
            if (bnd > a)
                k_prop3_bf16<<<((bnd - a) + 3) / 4, 256, 0, stream>>>(
                    col_ptr, srt_rp, pv_self, (const unsigned int*)zb, bias3, out, a, bnd);
        }
    }
}

// Round 13
// 342.910 us; speedup vs baseline: 1.1290x; 1.1290x over previous
//
#include <hip/hip_runtime.h>
#include <hip/hip_bf16.h>

#define NEG_SLOPE 0.1f
#define D1 128
#define D2 256

// bucket = 256 consecutive node ids (shift 8). Edge blocks = 4096 edges.
#define BSH 8
#define NPB 256
#define EPB 4096
#define MAXBUK 1024   // LDS arrays sized for NBUK <= 1024

__device__ __forceinline__ float leaky(float x) { return x >= 0.f ? x : NEG_SLOPE * x; }

__device__ __forceinline__ unsigned short f2bf(float x) {
    union { float f; unsigned int u; } v; v.f = x;
    unsigned int r = (v.u + 0x7FFFu + ((v.u >> 16) & 1u)) >> 16;   // RNE
    return (unsigned short)r;
}

__device__ __forceinline__ unsigned int pk2bf(float a, float b) {
    return (unsigned int)f2bf(a) | ((unsigned int)f2bf(b) << 16);
}

// scanned-table read with the block-partials fixup folded in
__device__ __forceinline__ int ts_g(const int* __restrict__ TS,
                                    const int* __restrict__ partials, int idx) {
    return TS[idx] + partials[idx >> 11];
}

// ---- pass A: per-(block,bucket) histograms for col-keys and row-keys ----
__global__ __launch_bounds__(256) void k_hist(const int* __restrict__ row,
                                              const int* __restrict__ col,
                                              int* __restrict__ T,
                                              int E, int NBLK, int NBUK)
{
    __shared__ int hc[MAXBUK], hr[MAXBUK];
    for (int b = threadIdx.x; b < NBUK; b += 256) { hc[b] = 0; hr[b] = 0; }
    __syncthreads();
    int base = blockIdx.x * EPB;
#pragma unroll 8
    for (int i = 0; i < EPB / 256; i++) {
        int e = base + i * 256 + threadIdx.x;
        if (e < E) {
            atomicAdd(&hc[col[e] >> BSH], 1);
            atomicAdd(&hr[row[e] >> BSH], 1);
        }
    }
    __syncthreads();
    int NT = NBUK * NBLK;
    for (int b = threadIdx.x; b < NBUK; b += 256) {
        T[b * NBLK + blockIdx.x]      = hc[b];
        T[NT + b * NBLK + blockIdx.x] = hr[b];
    }
}

// ---- exclusive scan: local pass + partials pass (fixup folded into readers) ----
__global__ __launch_bounds__(256) void k_scan_local(const int* __restrict__ in, int* __restrict__ out,
                                                    int* __restrict__ partials, int n)
{
    __shared__ int s[256];
    int base = blockIdx.x * 2048 + threadIdx.x * 8;
    int v[8]; int sum = 0;
#pragma unroll
    for (int i = 0; i < 8; i++) { v[i] = (base + i < n) ? in[base + i] : 0; sum += v[i]; }
    s[threadIdx.x] = sum;
    __syncthreads();
    for (int off = 1; off < 256; off <<= 1) {
        int t = (threadIdx.x >= off) ? s[threadIdx.x - off] : 0;
        __syncthreads();
        s[threadIdx.x] += t;
        __syncthreads();
    }
    int excl = s[threadIdx.x] - sum;
#pragma unroll
    for (int i = 0; i < 8; i++) { if (base + i < n) { out[base + i] = excl; excl += v[i]; } }
    if (threadIdx.x == 255) partials[blockIdx.x] = s[255];
}

// block 0: parallel exclusive scan of up to 1024 block partials.
// blocks 1..32: weight pre-convert to fragment-layout bf16:
//   w2f[((k>>3)*256 + m)*8 + (k&7)] = bf16(w2[m][k])   (m<256, k<128)
//   w3f[((k>>3)*128 + m)*8 + (k&7)] = bf16(w3[m][k])   (m<128, k<256)
__global__ __launch_bounds__(1024) void k_scan_cvt(int* __restrict__ partials, int nb,
                                                   const float* __restrict__ w2,
                                                   const float* __restrict__ w3,
                                                   unsigned short* __restrict__ w2f,
                                                   unsigned short* __restrict__ w3f)
{
    int t = threadIdx.x;
    if (blockIdx.x == 0) {
        __shared__ int s[1024];
        int v = (t < nb) ? partials[t] : 0;
        s[t] = v;
        __syncthreads();
        for (int off = 1; off < 1024; off <<= 1) {
            int u = (t >= off) ? s[t - off] : 0;
            __syncthreads();
            s[t] += u;
            __syncthreads();
        }
        if (t < nb) partials[t] = s[t] - v;
    } else {
        int i = (blockIdx.x - 1) * 1024 + t;    // 0 .. 32767 (both tables 32768 elems)
        {
            int m = i >> 7, k = i & 127;
            w2f[(((k >> 3) * 256 + m) << 3) + (k & 7)] = f2bf(w2[i]);
        }
        {
            int m = i >> 8, k = i & 255;
            w3f[(((k >> 3) * 128 + m) << 3) + (k & 7)] = f2bf(w3[i]);
        }
    }
}

// ---- pass B: scatter edges to col-bucket regions (X) and row-bucket regions (Y) ----
// X entry: .x = (c_local<<24) | r   (needs N < 2^24), .y = val bits
// Y entry: .x = r_local, .y = |val| bits
__global__ __launch_bounds__(256) void k_scat(const int* __restrict__ row,
                                              const int* __restrict__ col,
                                              const float* __restrict__ val,
                                              const int* __restrict__ TS,
                                              const int* __restrict__ partials,
                                              int2* __restrict__ X, int2* __restrict__ Y,
                                              int E, int NBLK, int NBUK)
{
    __shared__ int oc[MAXBUK], orw[MAXBUK];
    int NT = NBUK * NBLK;
    for (int b = threadIdx.x; b < NBUK; b += 256) {
        oc[b]  = ts_g(TS, partials, b * NBLK + blockIdx.x);
        orw[b] = ts_g(TS, partials, NT + b * NBLK + blockIdx.x);
    }
    __syncthreads();
    int base = blockIdx.x * EPB;
#pragma unroll 8
    for (int i = 0; i < EPB / 256; i++) {
        int e = base + i * 256 + threadIdx.x;
        if (e < E) {
            int r = row[e], c = col[e];
            float v = val[e];
            int pc = atomicAdd(&oc[c >> BSH], 1);
            X[pc] = make_int2(((c & (NPB - 1)) << 24) | r, __float_as_int(v));
            int pr = atomicAdd(&orw[r >> BSH], 1);
            Y[pr - E] = make_int2(r & (NPB - 1), __float_as_int(fabsf(v)));
        }
    }
}

// ---- pass C (row): per-row-bucket reduction -> dinv, pv_self ----
__global__ __launch_bounds__(256) void k_rowstats(const int2* __restrict__ Y,
                                                  const int* __restrict__ TS,
                                                  const int* __restrict__ partials,
                                                  float* __restrict__ dinv,
                                                  float* __restrict__ pv_self,
                                                  int N, int E, int NBLK, int NBUK)
{
    __shared__ float fs[NPB];
    __shared__ int   cn[NPB];
    int t = threadIdx.x;
    if (t < NPB) { fs[t] = 0.f; cn[t] = 0; }
    __syncthreads();
    int NT = NBUK * NBLK;
    int buk = blockIdx.x;
    int s = ts_g(TS, partials, NT + buk * NBLK);
    int e = (buk == NBUK - 1) ? 2 * E : ts_g(TS, partials, NT + (buk + 1) * NBLK);
    for (int j = s + t; j < e; j += 256) {
        int2 y = Y[j - E];
        atomicAdd(&fs[y.x], __int_as_float(y.y));
        atomicAdd(&cn[y.x], 1);
    }
    __syncthreads();
    if (t < NPB) {
        int node = buk * NPB + t;
        if (node < N) {
            float as = fs[t];
            float c  = (float)cn[t];
            float am = as / fmaxf(c, 1.f);
            float deg = as + am;
            float di = deg > 0.f ? rsqrtf(deg) : 0.f;
            dinv[node]    = di;
            pv_self[node] = am * di * di;
        }
    }
}

// ---- pass C (col): per-col-bucket node ranking -> col_ptr, srt_rp (r,pv), x1 ----
__global__ __launch_bounds__(256) void k_colfinal(const int2* __restrict__ X,
                                                  const int* __restrict__ TS,
                                                  const int* __restrict__ partials,
                                                  const float* __restrict__ dinv,
                                                  const float* __restrict__ pv_self,
                                                  int* __restrict__ col_ptr,
                                                  int2* __restrict__ srt_rp,
                                                  float* __restrict__ x1,
                                                  int N, int E, int NBLK, int NBUK)
{
    __shared__ int   hist[NPB];
    __shared__ int   tmp[NPB];
    __shared__ int   rb[NPB];
    __shared__ float xs[NPB];
    __shared__ float dl[NPB];
    int t = threadIdx.x;
    int buk = blockIdx.x;
    int node = buk * NPB + t;
    if (t < NPB) {
        hist[t] = 0; xs[t] = 0.f;
        dl[t] = (node < N) ? dinv[node] : 0.f;
    }
    __syncthreads();
    int s  = ts_g(TS, partials, buk * NBLK);
    int e2 = (buk == NBUK - 1) ? E : ts_g(TS, partials, (buk + 1) * NBLK);
    for (int j = s + t; j < e2; j += 256) {
        unsigned xw = (unsigned)X[j].x;
        atomicAdd(&hist[xw >> 24], 1);
    }
    __syncthreads();
    if (t < NPB) tmp[t] = hist[t];
    __syncthreads();
    for (int off = 1; off < NPB; off <<= 1) {
        int u = (t >= off && t < NPB) ? tmp[t - off] : 0;
        __syncthreads();
        if (t < NPB) tmp[t] += u;
        __syncthreads();
    }
    if (t < NPB) {
        int excl = tmp[t] - hist[t];
        rb[t] = s + excl;
        if (node < N) col_ptr[node] = s + excl;
    }
    if (buk == NBUK - 1 && t == 0) col_ptr[N] = E;
    __syncthreads();
    for (int j = s + t; j < e2; j += 256) {
        int2 xx = X[j];
        unsigned xw = (unsigned)xx.x;
        int cl = xw >> 24;
        int r  = (int)(xw & 0xFFFFFFu);
        float p = __int_as_float(xx.y) * dinv[r] * dl[cl];
        int pos = atomicAdd(&rb[cl], 1);
        srt_rp[pos] = make_int2(r, __float_as_int(p));
        atomicAdd(&xs[cl], p);
    }
    __syncthreads();
    if (t < NPB && node < N) x1[node] = pv_self[node] + xs[t];
}

// ---- conv2 propagate, broadcast form: one wave per node, 2 dims per lane.
// Output stored directly as bf16 (RNE). 4-edge hand-unroll (k ascending ->
// bitwise-identical accumulation order).
__global__ __launch_bounds__(256) void k_prop2b(const int* __restrict__ col_ptr,
                                                const int2* __restrict__ srt_rp,
                                                const float* __restrict__ pv_self,
                                                const float* __restrict__ x1,
                                                const float* __restrict__ w1,
                                                const float* __restrict__ b1,
                                                unsigned int* __restrict__ p2b, int N)
{
    int node = blockIdx.x * 4 + (threadIdx.x >> 6);
    int lane = threadIdx.x & 63;
    if (node >= N) return;

    float2 w = *(const float2*)&w1[lane * 2];
    float2 b = *(const float2*)&b1[lane * 2];
    float ps  = pv_self[node];
    float x1n = x1[node];
    float acc0 = ps * leaky(fmaf(x1n, w.x, b.x));
    float acc1 = ps * leaky(fmaf(x1n, w.y, b.y));

    int s = col_ptr[node], e = col_ptr[node + 1];
    for (int base = s; base < e; base += 64) {
        int mc = min(64, e - base);
        float p = 0.f, sv = 0.f;
        if (lane < mc) {
            int2 rp = srt_rp[base + lane];
            p  = __int_as_float(rp.y);
            sv = x1[rp.x];
        }
        int k = 0;
        for (; k + 3 < mc; k += 4) {
            float pk0 = __shfl(p, k, 64),     sk0 = __shfl(sv, k, 64);
            float pk1 = __shfl(p, k + 1, 64), sk1 = __shfl(sv, k + 1, 64);
            float pk2 = __shfl(p, k + 2, 64), sk2 = __shfl(sv, k + 2, 64);
            float pk3 = __shfl(p, k + 3, 64), sk3 = __shfl(sv, k + 3, 64);
            acc0 += pk0 * leaky(fmaf(sk0, w.x, b.x));
            acc1 += pk0 * leaky(fmaf(sk0, w.y, b.y));
            acc0 += pk1 * leaky(fmaf(sk1, w.x, b.x));
            acc1 += pk1 * leaky(fmaf(sk1, w.y, b.y));
            acc0 += pk2 * leaky(fmaf(sk2, w.x, b.x));
            acc1 += pk2 * leaky(fmaf(sk2, w.y, b.y));
            acc0 += pk3 * leaky(fmaf(sk3, w.x, b.x));
            acc1 += pk3 * leaky(fmaf(sk3, w.y, b.y));
        }
        for (; k < mc; ++k) {
            float pk = __shfl(p, k, 64);
            float sk = __shfl(sv, k, 64);
            acc0 += pk * leaky(fmaf(sk, w.x, b.x));
            acc1 += pk * leaky(fmaf(sk, w.y, b.y));
        }
    }

    p2b[(size_t)node * 64 + lane] = pk2bf(acc0, acc1);
}

// ---- conv3 gather propagate over bf16 z, one wave per node, 4-edge unroll ----
__global__ __launch_bounds__(256) void k_prop3_bf16(const int* __restrict__ col_ptr,
                                                    const int2* __restrict__ srt_rp,
                                                    const float* __restrict__ pv_self,
                                                    const unsigned int* __restrict__ zb,
                                                    const float* __restrict__ bias3,
                                                    float* __restrict__ out, int N)
{
    int node = blockIdx.x * 4 + (threadIdx.x >> 6);
    int lane = threadIdx.x & 63;
    if (node >= N) return;

    unsigned int us = zb[(size_t)node * 64 + lane];
    float ps = pv_self[node];
    float acc0 = ps * __uint_as_float(us << 16);
    float acc1 = ps * __uint_as_float(us & 0xFFFF0000u);

    int j = col_ptr[node], e = col_ptr[node + 1];
    for (; j + 3 < e; j += 4) {
        int2 rp0 = srt_rp[j];
        int2 rp1 = srt_rp[j + 1];
        int2 rp2 = srt_rp[j + 2];
        int2 rp3 = srt_rp[j + 3];
        unsigned int u0 = zb[(size_t)rp0.x * 64 + lane];
        unsigned int u1 = zb[(size_t)rp1.x * 64 + lane];
        unsigned int u2 = zb[(size_t)rp2.x * 64 + lane];
        unsigned int u3 = zb[(size_t)rp3.x * 64 + lane];
        float p0 = __int_as_float(rp0.y);
        float p1 = __int_as_float(rp1.y);
        float p2 = __int_as_float(rp2.y);
        float p3 = __int_as_float(rp3.y);
        acc0 += p0 * __uint_as_float(u0 << 16);
        acc1 += p0 * __uint_as_float(u0 & 0xFFFF0000u);
        acc0 += p1 * __uint_as_float(u1 << 16);
        acc1 += p1 * __uint_as_float(u1 & 0xFFFF0000u);
        acc0 += p2 * __uint_as_float(u2 << 16);
        acc1 += p2 * __uint_as_float(u2 & 0xFFFF0000u);
        acc0 += p3 * __uint_as_float(u3 << 16);
        acc1 += p3 * __uint_as_float(u3 & 0xFFFF0000u);
    }
    for (; j < e; ++j) {
        int2 rp = srt_rp[j];
        unsigned int u = zb[(size_t)rp.x * 64 + lane];
        float p = __int_as_float(rp.y);
        acc0 += p * __uint_as_float(u << 16);
        acc1 += p * __uint_as_float(u & 0xFFFF0000u);
    }

    float2 b = *(const float2*)&bias3[lane * 2];
    float2 o = make_float2(leaky(acc0 + b.x), leaky(acc1 + b.y));
    *(float2*)&out[(size_t)node * D1 + lane * 2] = o;
}

// ---- fused MFMA GEMM chain v4: full fragment preload (ILP over TLP) ----
__global__ __launch_bounds__(256, 2) void k_gemm_fused4(const unsigned int* __restrict__ p2b,
                                                        const unsigned short* __restrict__ w2f,
                                                        const float* __restrict__ b2,
                                                        const float* __restrict__ bias2,
                                                        const unsigned short* __restrict__ w3f,
                                                        const float* __restrict__ b3,
                                                        const float* __restrict__ x1,
                                                        unsigned short* __restrict__ zb,
                                                        int N)
{
    typedef __attribute__((ext_vector_type(8))) short short8v;
    typedef __attribute__((ext_vector_type(4))) float f32x4;

    __shared__ unsigned short H[32 * 64 * 8];   // H^T tile, [w2col/8][node][8], 32 KB

    const int t = threadIdx.x;
    const int n_base = blockIdx.x * 64;
    const int l  = t & 63, wid = t >> 6;
    const int lr = l & 15, lk = l >> 4;

    // ---- phase 1 preload: all 16 w2 frags + all 16 p2 frags ----
    short8v a1[4][4], p1[4][4];
#pragma unroll
    for (int ks = 0; ks < 4; ks++) {
        const int k0 = ks * 32;
#pragma unroll
        for (int i = 0; i < 4; i++)
            a1[ks][i] = *(const short8v*)&w2f[((((k0 >> 3) + lk) * 256) + wid * 64 + i * 16 + lr) * 8];
#pragma unroll
        for (int j = 0; j < 4; j++) {
            int node = n_base + j * 16 + lr;
            if (node >= N) node = N - 1;
            p1[ks][j] = *(const short8v*)&p2b[(size_t)node * 64 + (k0 >> 1) + lk * 4];
        }
    }

    // ---- phase 1 MFMA burst: wave owns w2cols [wid*64, wid*64+64) ----
    f32x4 acc1[4][4] = {};
#pragma unroll
    for (int ks = 0; ks < 4; ks++)
#pragma unroll
        for (int i = 0; i < 4; i++)
#pragma unroll
            for (int j = 0; j < 4; j++)
                acc1[i][j] = __builtin_amdgcn_mfma_f32_16x16x32_bf16(a1[ks][i], p1[ks][j], acc1[i][j], 0, 0, 0);

    // ---- phase 2 weight preload (overlaps epilogue 1; a1/p1 regs are dead) ----
    short8v a2[8][2];
#pragma unroll
    for (int ks = 0; ks < 8; ks++) {
        const int k0 = ks * 32;
#pragma unroll
        for (int i = 0; i < 2; i++)
            a2[ks][i] = *(const short8v*)&w3f[((((k0 >> 3) + lk) * 128) + wid * 32 + i * 16 + lr) * 8];
    }

    // ---- epilogue 1 -> H (packed b64 writes; k-quads are lane-local) ----
    {
        float xv[4];
#pragma unroll
        for (int j = 0; j < 4; j++) {
            int node = n_base + j * 16 + lr;
            xv[j] = (node < N) ? x1[node] : 0.f;
        }
#pragma unroll
        for (int i = 0; i < 4; i++) {
            const int c0 = wid * 64 + i * 16 + lk * 4;   // 4 consecutive w2cols
            float4 bq  = *(const float4*)&b2[c0];
            float4 biq = *(const float4*)&bias2[c0];
            const int kblk = wid * 8 + i * 2 + (lk >> 1);
#pragma unroll
            for (int j = 0; j < 4; j++) {
                float v0 = leaky(acc1[i][j][0] + xv[j] * bq.x + biq.x);
                float v1 = leaky(acc1[i][j][1] + xv[j] * bq.y + biq.y);
                float v2 = leaky(acc1[i][j][2] + xv[j] * bq.z + biq.z);
                float v3 = leaky(acc1[i][j][3] + xv[j] * bq.w + biq.w);
                uint2 pk = make_uint2(pk2bf(v0, v1), pk2bf(v2, v3));
                *(uint2*)&H[(kblk * 64 + j * 16 + lr) * 8 + (lk & 1) * 4] = pk;
            }
        }
    }
    __syncthreads();

    // ---- phase 2: wave owns w3cols [wid*32, wid*32+32); H from LDS ----
    f32x4 acc2[2][4] = {};
#pragma unroll
    for (int ks = 0; ks < 8; ks++) {
        const int k0 = ks * 32;
        short8v bf[4];
#pragma unroll
        for (int j = 0; j < 4; j++)
            bf[j] = *(const short8v*)&H[(((k0 >> 3) + lk) * 64 + j * 16 + lr) * 8];
#pragma unroll
        for (int i = 0; i < 2; i++)
#pragma unroll
            for (int j = 0; j < 4; j++)
                acc2[i][j] = __builtin_amdgcn_mfma_f32_16x16x32_bf16(a2[ks][i], bf[j], acc2[i][j], 0, 0, 0);
    }

    // ---- epilogue 2 -> zb (packed ushort4 stores) ----
#pragma unroll
    for (int i = 0; i < 2; i++) {
        const int m0 = wid * 32 + i * 16 + lk * 4;   // 4 consecutive z-cols
        float4 bq = *(const float4*)&b3[m0];
#pragma unroll
        for (int j = 0; j < 4; j++) {
            int node = n_base + j * 16 + lr;
            if (node < N) {
                ushort4 s4;
                s4.x = f2bf(acc2[i][j][0] + bq.x);
                s4.y = f2bf(acc2[i][j][1] + bq.y);
                s4.z = f2bf(acc2[i][j][2] + bq.z);
                s4.w = f2bf(acc2[i][j][3] + bq.w);
                *(ushort4*)&zb[(size_t)node * D1 + m0] = s4;
            }
        }
    }
}

extern "C" void kernel_launch(void* const* d_in, const int* in_sizes, int n_in,
                              void* d_out, int out_size, void* d_ws, size_t ws_size,
                              hipStream_t stream)
{
    const int* ei       = (const int*)d_in[0];     // (2,E) int32
    const float* val    = (const float*)d_in[1];   // (E,)
    const float* w1     = (const float*)d_in[3];   // (128,1)
    const float* b1     = (const float*)d_in[4];   // (128,)
    const float* w2     = (const float*)d_in[5];   // (256,128)
    const float* b2     = (const float*)d_in[6];   // (256,)
    const float* bias2  = (const float*)d_in[7];   // (256,)
    const float* w3     = (const float*)d_in[8];   // (128,256)
    const float* b3     = (const float*)d_in[9];   // (128,)
    const float* bias3  = (const float*)d_in[10];  // (128,)
    float* out = (float*)d_out;

    const int E = in_sizes[1];
    const int N = out_size / D1;
    const int* row = ei;
    const int* col = ei + E;

    const int NBLK = (E + EPB - 1) / EPB;          // edge blocks (391 @ E=1.6M)
    const int NBUK = (N + NPB - 1) >> BSH;         // node buckets (391 @ N=100K)
    const int NT   = NBUK * NBLK;

    // workspace layout
    float* dinv    = (float*)d_ws;                                   // N
    float* pv_self = dinv + N;                                       // N
    float* x1      = pv_self + N;                                    // N
    int*   col_ptr = (int*)(x1 + N);                                 // N+8
    int*   partials= col_ptr + N + 8;                                // 1024
    int2*  srt_rp  = (int2*)(partials + 1024);                       // E int2
    unsigned int* p2b = (unsigned int*)(srt_rp + (size_t)E);         // N*64 uints (bf16 p2)
    int*   TS      = (int*)(p2b + (size_t)N * 64);                   // 2*NT scanned table
    int*   T       = TS + (size_t)2 * NT;                            // 2*NT raw histograms
    int2*  Y       = (int2*)(T + (size_t)2 * NT);                    // E (row-bucketed edges)
    unsigned short* w2f = (unsigned short*)(Y + (size_t)E);          // 32768 bf16 (frag layout)
    unsigned short* w3f = w2f + 32768;                               // 32768 bf16 (frag layout)
    unsigned short* zb  = w3f + 32768;                               // N*128 bf16 z (de-aliased)
    // alias:
    int2* X = (int2*)p2b;                    // E entries; dead before k_prop2b writes p2b (E*8 <= N*256)

    const int B = 256;
    const int n2 = 2 * NT;
    const int scan_blocks = (n2 + 2047) / 2048;    // 150 @ default sizes (<= 1024)

    // bucket-sort pipeline: LDS atomics only, zero global atomics, no memsets
    k_hist<<<NBLK, B, 0, stream>>>(row, col, T, E, NBLK, NBUK);
    k_scan_local<<<scan_blocks, 256, 0, stream>>>(T, TS, partials, n2);
    k_scan_cvt<<<33, 1024, 0, stream>>>(partials, scan_blocks, w2, w3, w2f, w3f);
    k_scat<<<NBLK, B, 0, stream>>>(row, col, val, TS, partials, X, Y, E, NBLK, NBUK);
    k_rowstats<<<NBUK, B, 0, stream>>>(Y, TS, partials, dinv, pv_self, N, E, NBLK, NBUK);
    k_colfinal<<<NBUK, B, 0, stream>>>(X, TS, partials, dinv, pv_self, col_ptr, srt_rp, x1, N, E, NBLK, NBUK);

    // conv2 propagate -> bf16 p2, then fused MFMA chain p2 -> H(LDS) -> z
    k_prop2b<<<(N + 3) / 4, 256, 0, stream>>>(col_ptr, srt_rp, pv_self, x1, w1, b1, p2b, N);
    k_gemm_fused4<<<(N + 63) / 64, 256, 0, stream>>>(p2b, w2f, b2, bias2, w3f, b3, x1, zb, N);

    // conv3 gather propagate + fused bias3/leaky
    k_prop3_bf16<<<(N + 3) / 4, 256, 0, stream>>>(col_ptr, srt_rp, pv_self, (const unsigned int*)zb, bias3, out, N);
}

// Round 14
// 336.591 us; speedup vs baseline: 1.1502x; 1.0188x over previous
//
#include <hip/hip_runtime.h>
#include <hip/hip_bf16.h>

#define NEG_SLOPE 0.1f
#define D1 128
#define D2 256

// bucket = 256 consecutive node ids (shift 8). Edge blocks = 4096 edges.
#define BSH 8
#define NPB 256
#define EPB 4096
#define MAXBUK 1024   // LDS arrays sized for NBUK <= 1024

__device__ __forceinline__ float leaky(float x) { return x >= 0.f ? x : NEG_SLOPE * x; }

__device__ __forceinline__ unsigned short f2bf(float x) {
    union { float f; unsigned int u; } v; v.f = x;
    unsigned int r = (v.u + 0x7FFFu + ((v.u >> 16) & 1u)) >> 16;   // RNE
    return (unsigned short)r;
}

__device__ __forceinline__ unsigned int pk2bf(float a, float b) {
    return (unsigned int)f2bf(a) | ((unsigned int)f2bf(b) << 16);
}

// scanned-table read with the block-partials fixup folded in
__device__ __forceinline__ int ts_g(const int* __restrict__ TS,
                                    const int* __restrict__ partials, int idx) {
    return TS[idx] + partials[idx >> 11];
}

// ---- pass A: per-(block,bucket) histograms, 1024 threads (4 edges/thread) ----
__global__ __launch_bounds__(1024) void k_hist(const int* __restrict__ row,
                                               const int* __restrict__ col,
                                               int* __restrict__ T,
                                               int E, int NBLK, int NBUK)
{
    __shared__ int hc[MAXBUK], hr[MAXBUK];
    for (int b = threadIdx.x; b < NBUK; b += 1024) { hc[b] = 0; hr[b] = 0; }
    __syncthreads();
    int base = blockIdx.x * EPB;
#pragma unroll 4
    for (int i = 0; i < EPB / 1024; i++) {
        int e = base + i * 1024 + threadIdx.x;
        if (e < E) {
            atomicAdd(&hc[col[e] >> BSH], 1);
            atomicAdd(&hr[row[e] >> BSH], 1);
        }
    }
    __syncthreads();
    int NT = NBUK * NBLK;
    for (int b = threadIdx.x; b < NBUK; b += 1024) {
        T[b * NBLK + blockIdx.x]      = hc[b];
        T[NT + b * NBLK + blockIdx.x] = hr[b];
    }
}

// ---- exclusive scan: local pass + partials pass (fixup folded into readers) ----
__global__ __launch_bounds__(256) void k_scan_local(const int* __restrict__ in, int* __restrict__ out,
                                                    int* __restrict__ partials, int n)
{
    __shared__ int s[256];
    int base = blockIdx.x * 2048 + threadIdx.x * 8;
    int v[8]; int sum = 0;
#pragma unroll
    for (int i = 0; i < 8; i++) { v[i] = (base + i < n) ? in[base + i] : 0; sum += v[i]; }
    s[threadIdx.x] = sum;
    __syncthreads();
    for (int off = 1; off < 256; off <<= 1) {
        int t = (threadIdx.x >= off) ? s[threadIdx.x - off] : 0;
        __syncthreads();
        s[threadIdx.x] += t;
        __syncthreads();
    }
    int excl = s[threadIdx.x] - sum;
#pragma unroll
    for (int i = 0; i < 8; i++) { if (base + i < n) { out[base + i] = excl; excl += v[i]; } }
    if (threadIdx.x == 255) partials[blockIdx.x] = s[255];
}

// block 0: parallel exclusive scan of up to 1024 block partials.
// blocks 1..32: weight pre-convert to fragment-layout bf16:
//   w2f[((k>>3)*256 + m)*8 + (k&7)] = bf16(w2[m][k])   (m<256, k<128)
//   w3f[((k>>3)*128 + m)*8 + (k&7)] = bf16(w3[m][k])   (m<128, k<256)
__global__ __launch_bounds__(1024) void k_scan_cvt(int* __restrict__ partials, int nb,
                                                   const float* __restrict__ w2,
                                                   const float* __restrict__ w3,
                                                   unsigned short* __restrict__ w2f,
                                                   unsigned short* __restrict__ w3f)
{
    int t = threadIdx.x;
    if (blockIdx.x == 0) {
        __shared__ int s[1024];
        int v = (t < nb) ? partials[t] : 0;
        s[t] = v;
        __syncthreads();
        for (int off = 1; off < 1024; off <<= 1) {
            int u = (t >= off) ? s[t - off] : 0;
            __syncthreads();
            s[t] += u;
            __syncthreads();
        }
        if (t < nb) partials[t] = s[t] - v;
    } else {
        int i = (blockIdx.x - 1) * 1024 + t;    // 0 .. 32767 (both tables 32768 elems)
        {
            int m = i >> 7, k = i & 127;
            w2f[(((k >> 3) * 256 + m) << 3) + (k & 7)] = f2bf(w2[i]);
        }
        {
            int m = i >> 8, k = i & 255;
            w3f[(((k >> 3) * 128 + m) << 3) + (k & 7)] = f2bf(w3[i]);
        }
    }
}

// ---- pass B: scatter edges to col-bucket regions (X) and row-bucket regions (Y),
// 1024 threads (4 edges/thread) for latency hiding on scattered 8B writes ----
// X entry: .x = (c_local<<24) | r   (needs N < 2^24), .y = val bits
// Y entry: .x = r_local, .y = |val| bits
__global__ __launch_bounds__(1024) void k_scat(const int* __restrict__ row,
                                               const int* __restrict__ col,
                                               const float* __restrict__ val,
                                               const int* __restrict__ TS,
                                               const int* __restrict__ partials,
                                               int2* __restrict__ X, int2* __restrict__ Y,
                                               int E, int NBLK, int NBUK)
{
    __shared__ int oc[MAXBUK], orw[MAXBUK];
    int NT = NBUK * NBLK;
    for (int b = threadIdx.x; b < NBUK; b += 1024) {
        oc[b]  = ts_g(TS, partials, b * NBLK + blockIdx.x);
        orw[b] = ts_g(TS, partials, NT + b * NBLK + blockIdx.x);
    }
    __syncthreads();
    int base = blockIdx.x * EPB;
#pragma unroll 4
    for (int i = 0; i < EPB / 1024; i++) {
        int e = base + i * 1024 + threadIdx.x;
        if (e < E) {
            int r = row[e], c = col[e];
            float v = val[e];
            int pc = atomicAdd(&oc[c >> BSH], 1);
            X[pc] = make_int2(((c & (NPB - 1)) << 24) | r, __float_as_int(v));
            int pr = atomicAdd(&orw[r >> BSH], 1);
            Y[pr - E] = make_int2(r & (NPB - 1), __float_as_int(fabsf(v)));
        }
    }
}

// ---- pass C (row): per-row-bucket reduction -> dinv, pv_self (512 thr) ----
__global__ __launch_bounds__(512) void k_rowstats(const int2* __restrict__ Y,
                                                  const int* __restrict__ TS,
                                                  const int* __restrict__ partials,
                                                  float* __restrict__ dinv,
                                                  float* __restrict__ pv_self,
                                                  int N, int E, int NBLK, int NBUK)
{
    __shared__ float fs[NPB];
    __shared__ int   cn[NPB];
    int t = threadIdx.x;
    if (t < NPB) { fs[t] = 0.f; cn[t] = 0; }
    __syncthreads();
    int NT = NBUK * NBLK;
    int buk = blockIdx.x;
    int s = ts_g(TS, partials, NT + buk * NBLK);
    int e = (buk == NBUK - 1) ? 2 * E : ts_g(TS, partials, NT + (buk + 1) * NBLK);
    for (int j = s + t; j < e; j += 512) {
        int2 y = Y[j - E];
        atomicAdd(&fs[y.x], __int_as_float(y.y));
        atomicAdd(&cn[y.x], 1);
    }
    __syncthreads();
    if (t < NPB) {
        int node = buk * NPB + t;
        if (node < N) {
            float as = fs[t];
            float c  = (float)cn[t];
            float am = as / fmaxf(c, 1.f);
            float deg = as + am;
            float di = deg > 0.f ? rsqrtf(deg) : 0.f;
            dinv[node]    = di;
            pv_self[node] = am * di * di;
        }
    }
}

// ---- pass C (col): per-col-bucket node ranking -> col_ptr, srt_rp, x1 (512 thr) ----
__global__ __launch_bounds__(512) void k_colfinal(const int2* __restrict__ X,
                                                  const int* __restrict__ TS,
                                                  const int* __restrict__ partials,
                                                  const float* __restrict__ dinv,
                                                  const float* __restrict__ pv_self,
                                                  int* __restrict__ col_ptr,
                                                  int2* __restrict__ srt_rp,
                                                  float* __restrict__ x1,
                                                  int N, int E, int NBLK, int NBUK)
{
    __shared__ int   hist[NPB];
    __shared__ int   tmp[NPB];
    __shared__ int   rb[NPB];
    __shared__ float xs[NPB];
    __shared__ float dl[NPB];
    int t = threadIdx.x;
    int buk = blockIdx.x;
    int node = buk * NPB + t;
    if (t < NPB) {
        hist[t] = 0; xs[t] = 0.f;
        dl[t] = (node < N) ? dinv[node] : 0.f;
    }
    __syncthreads();
    int s  = ts_g(TS, partials, buk * NBLK);
    int e2 = (buk == NBUK - 1) ? E : ts_g(TS, partials, (buk + 1) * NBLK);
    for (int j = s + t; j < e2; j += 512) {
        unsigned xw = (unsigned)X[j].x;
        atomicAdd(&hist[xw >> 24], 1);
    }
    __syncthreads();
    if (t < NPB) tmp[t] = hist[t];
    __syncthreads();
    for (int off = 1; off < NPB; off <<= 1) {
        int u = (t >= off && t < NPB) ? tmp[t - off] : 0;
        __syncthreads();
        if (t < NPB) tmp[t] += u;
        __syncthreads();
    }
    if (t < NPB) {
        int excl = tmp[t] - hist[t];
        rb[t] = s + excl;
        if (node < N) col_ptr[node] = s + excl;
    }
    if (buk == NBUK - 1 && t == 0) col_ptr[N] = E;
    __syncthreads();
    for (int j = s + t; j < e2; j += 512) {
        int2 xx = X[j];
        unsigned xw = (unsigned)xx.x;
        int cl = xw >> 24;
        int r  = (int)(xw & 0xFFFFFFu);
        float p = __int_as_float(xx.y) * dinv[r] * dl[cl];
        int pos = atomicAdd(&rb[cl], 1);
        srt_rp[pos] = make_int2(r, __float_as_int(p));
        atomicAdd(&xs[cl], p);
    }
    __syncthreads();
    if (t < NPB && node < N) x1[node] = pv_self[node] + xs[t];
}

// ---- conv2 propagate, broadcast form: one wave per node, 2 dims per lane.
// Output stored directly as bf16 (RNE). 4-edge hand-unroll (k ascending ->
// bitwise-identical accumulation order).
__global__ __launch_bounds__(256) void k_prop2b(const int* __restrict__ col_ptr,
                                                const int2* __restrict__ srt_rp,
                                                const float* __restrict__ pv_self,
                                                const float* __restrict__ x1,
                                                const float* __restrict__ w1,
                                                const float* __restrict__ b1,
                                                unsigned int* __restrict__ p2b, int N)
{
    int node = blockIdx.x * 4 + (threadIdx.x >> 6);
    int lane = threadIdx.x & 63;
    if (node >= N) return;

    float2 w = *(const float2*)&w1[lane * 2];
    float2 b = *(const float2*)&b1[lane * 2];
    float ps  = pv_self[node];
    float x1n = x1[node];
    float acc0 = ps * leaky(fmaf(x1n, w.x, b.x));
    float acc1 = ps * leaky(fmaf(x1n, w.y, b.y));

    int s = col_ptr[node], e = col_ptr[node + 1];
    for (int base = s; base < e; base += 64) {
        int mc = min(64, e - base);
        float p = 0.f, sv = 0.f;
        if (lane < mc) {
            int2 rp = srt_rp[base + lane];
            p  = __int_as_float(rp.y);
            sv = x1[rp.x];
        }
        int k = 0;
        for (; k + 3 < mc; k += 4) {
            float pk0 = __shfl(p, k, 64),     sk0 = __shfl(sv, k, 64);
            float pk1 = __shfl(p, k + 1, 64), sk1 = __shfl(sv, k + 1, 64);
            float pk2 = __shfl(p, k + 2, 64), sk2 = __shfl(sv, k + 2, 64);
            float pk3 = __shfl(p, k + 3, 64), sk3 = __shfl(sv, k + 3, 64);
            acc0 += pk0 * leaky(fmaf(sk0, w.x, b.x));
            acc1 += pk0 * leaky(fmaf(sk0, w.y, b.y));
            acc0 += pk1 * leaky(fmaf(sk1, w.x, b.x));
            acc1 += pk1 * leaky(fmaf(sk1, w.y, b.y));
            acc0 += pk2 * leaky(fmaf(sk2, w.x, b.x));
            acc1 += pk2 * leaky(fmaf(sk2, w.y, b.y));
            acc0 += pk3 * leaky(fmaf(sk3, w.x, b.x));
            acc1 += pk3 * leaky(fmaf(sk3, w.y, b.y));
        }
        for (; k < mc; ++k) {
            float pk = __shfl(p, k, 64);
            float sk = __shfl(sv, k, 64);
            acc0 += pk * leaky(fmaf(sk, w.x, b.x));
            acc1 += pk * leaky(fmaf(sk, w.y, b.y));
        }
    }

    p2b[(size_t)node * 64 + lane] = pk2bf(acc0, acc1);
}

// ---- conv3 gather propagate over bf16 z, one wave per node, 4-edge unroll ----
__global__ __launch_bounds__(256) void k_prop3_bf16(const int* __restrict__ col_ptr,
                                                    const int2* __restrict__ srt_rp,
                                                    const float* __restrict__ pv_self,
                                                    const unsigned int* __restrict__ zb,
                                                    const float* __restrict__ bias3,
                                                    float* __restrict__ out, int N)
{
    int node = blockIdx.x * 4 + (threadIdx.x >> 6);
    int lane = threadIdx.x & 63;
    if (node >= N) return;

    unsigned int us = zb[(size_t)node * 64 + lane];
    float ps = pv_self[node];
    float acc0 = ps * __uint_as_float(us << 16);
    float acc1 = ps * __uint_as_float(us & 0xFFFF0000u);

    int j = col_ptr[node], e = col_ptr[node + 1];
    for (; j + 3 < e; j += 4) {
        int2 rp0 = srt_rp[j];
        int2 rp1 = srt_rp[j + 1];
        int2 rp2 = srt_rp[j + 2];
        int2 rp3 = srt_rp[j + 3];
        unsigned int u0 = zb[(size_t)rp0.x * 64 + lane];
        unsigned int u1 = zb[(size_t)rp1.x * 64 + lane];
        unsigned int u2 = zb[(size_t)rp2.x * 64 + lane];
        unsigned int u3 = zb[(size_t)rp3.x * 64 + lane];
        float p0 = __int_as_float(rp0.y);
        float p1 = __int_as_float(rp1.y);
        float p2 = __int_as_float(rp2.y);
        float p3 = __int_as_float(rp3.y);
        acc0 += p0 * __uint_as_float(u0 << 16);
        acc1 += p0 * __uint_as_float(u0 & 0xFFFF0000u);
        acc0 += p1 * __uint_as_float(u1 << 16);
        acc1 += p1 * __uint_as_float(u1 & 0xFFFF0000u);
        acc0 += p2 * __uint_as_float(u2 << 16);
        acc1 += p2 * __uint_as_float(u2 & 0xFFFF0000u);
        acc0 += p3 * __uint_as_float(u3 << 16);
        acc1 += p3 * __uint_as_float(u3 & 0xFFFF0000u);
    }
    for (; j < e; ++j) {
        int2 rp = srt_rp[j];
        unsigned int u = zb[(size_t)rp.x * 64 + lane];
        float p = __int_as_float(rp.y);
        acc0 += p * __uint_as_float(u << 16);
        acc1 += p * __uint_as_float(u & 0xFFFF0000u);
    }

    float2 b = *(const float2*)&bias3[lane * 2];
    float2 o = make_float2(leaky(acc0 + b.x), leaky(acc1 + b.y));
    *(float2*)&out[(size_t)node * D1 + lane * 2] = o;
}

// ---- fused MFMA GEMM chain v4: full fragment preload (ILP over TLP) ----
__global__ __launch_bounds__(256, 2) void k_gemm_fused4(const unsigned int* __restrict__ p2b,
                                                        const unsigned short* __restrict__ w2f,
                                                        const float* __restrict__ b2,
                                                        const float* __restrict__ bias2,
                                                        const unsigned short* __restrict__ w3f,
                                                        const float* __restrict__ b3,
                                                        const float* __restrict__ x1,
                                                        unsigned short* __restrict__ zb,
                                                        int N)
{
    typedef __attribute__((ext_vector_type(8))) short short8v;
    typedef __attribute__((ext_vector_type(4))) float f32x4;

    __shared__ unsigned short H[32 * 64 * 8];   // H^T tile, [w2col/8][node][8], 32 KB

    const int t = threadIdx.x;
    const int n_base = blockIdx.x * 64;
    const int l  = t & 63, wid = t >> 6;
    const int lr = l & 15, lk = l >> 4;

    // ---- phase 1 preload: all 16 w2 frags + all 16 p2 frags ----
    short8v a1[4][4], p1[4][4];
#pragma unroll
    for (int ks = 0; ks < 4; ks++) {
        const int k0 = ks * 32;
#pragma unroll
        for (int i = 0; i < 4; i++)
            a1[ks][i] = *(const short8v*)&w2f[((((k0 >> 3) + lk) * 256) + wid * 64 + i * 16 + lr) * 8];
#pragma unroll
        for (int j = 0; j < 4; j++) {
            int node = n_base + j * 16 + lr;
            if (node >= N) node = N - 1;
            p1[ks][j] = *(const short8v*)&p2b[(size_t)node * 64 + (k0 >> 1) + lk * 4];
        }
    }

    // ---- phase 1 MFMA burst: wave owns w2cols [wid*64, wid*64+64) ----
    f32x4 acc1[4][4] = {};
#pragma unroll
    for (int ks = 0; ks < 4; ks++)
#pragma unroll
        for (int i = 0; i < 4; i++)
#pragma unroll
            for (int j = 0; j < 4; j++)
                acc1[i][j] = __builtin_amdgcn_mfma_f32_16x16x32_bf16(a1[ks][i], p1[ks][j], acc1[i][j], 0, 0, 0);

    // ---- phase 2 weight preload (overlaps epilogue 1; a1/p1 regs are dead) ----
    short8v a2[8][2];
#pragma unroll
    for (int ks = 0; ks < 8; ks++) {
        const int k0 = ks * 32;
#pragma unroll
        for (int i = 0; i < 2; i++)
            a2[ks][i] = *(const short8v*)&w3f[((((k0 >> 3) + lk) * 128) + wid * 32 + i * 16 + lr) * 8];
    }

    // ---- epilogue 1 -> H (packed b64 writes; k-quads are lane-local) ----
    {
        float xv[4];
#pragma unroll
        for (int j = 0; j < 4; j++) {
            int node = n_base + j * 16 + lr;
            xv[j] = (node < N) ? x1[node] : 0.f;
        }
#pragma unroll
        for (int i = 0; i < 4; i++) {
            const int c0 = wid * 64 + i * 16 + lk * 4;   // 4 consecutive w2cols
            float4 bq  = *(const float4*)&b2[c0];
            float4 biq = *(const float4*)&bias2[c0];
            const int kblk = wid * 8 + i * 2 + (lk >> 1);
#pragma unroll
            for (int j = 0; j < 4; j++) {
                float v0 = leaky(acc1[i][j][0] + xv[j] * bq.x + biq.x);
                float v1 = leaky(acc1[i][j][1] + xv[j] * bq.y + biq.y);
                float v2 = leaky(acc1[i][j][2] + xv[j] * bq.z + biq.z);
                float v3 = leaky(acc1[i][j][3] + xv[j] * bq.w + biq.w);
                uint2 pk = make_uint2(pk2bf(v0, v1), pk2bf(v2, v3));
                *(uint2*)&H[(kblk * 64 + j * 16 + lr) * 8 + (lk & 1) * 4] = pk;
            }
        }
    }
    __syncthreads();

    // ---- phase 2: wave owns w3cols [wid*32, wid*32+32); H from LDS ----
    f32x4 acc2[2][4] = {};
#pragma unroll
    for (int ks = 0; ks < 8; ks++) {
        const int k0 = ks * 32;
        short8v bf[4];
#pragma unroll
        for (int j = 0; j < 4; j++)
            bf[j] = *(const short8v*)&H[(((k0 >> 3) + lk) * 64 + j * 16 + lr) * 8];
#pragma unroll
        for (int i = 0; i < 2; i++)
#pragma unroll
            for (int j = 0; j < 4; j++)
                acc2[i][j] = __builtin_amdgcn_mfma_f32_16x16x32_bf16(a2[ks][i], bf[j], acc2[i][j], 0, 0, 0);
    }

    // ---- epilogue 2 -> zb (packed ushort4 stores) ----
#pragma unroll
    for (int i = 0; i < 2; i++) {
        const int m0 = wid * 32 + i * 16 + lk * 4;   // 4 consecutive z-cols
        float4 bq = *(const float4*)&b3[m0];
#pragma unroll
        for (int j = 0; j < 4; j++) {
            int node = n_base + j * 16 + lr;
            if (node < N) {
                ushort4 s4;
                s4.x = f2bf(acc2[i][j][0] + bq.x);
                s4.y = f2bf(acc2[i][j][1] + bq.y);
                s4.z = f2bf(acc2[i][j][2] + bq.z);
                s4.w = f2bf(acc2[i][j][3] + bq.w);
                *(ushort4*)&zb[(size_t)node * D1 + m0] = s4;
            }
        }
    }
}

extern "C" void kernel_launch(void* const* d_in, const int* in_sizes, int n_in,
                              void* d_out, int out_size, void* d_ws, size_t ws_size,
                              hipStream_t stream)
{
    const int* ei       = (const int*)d_in[0];     // (2,E) int32
    const float* val    = (const float*)d_in[1];   // (E,)
    const float* w1     = (const float*)d_in[3];   // (128,1)
    const float* b1     = (const float*)d_in[4];   // (128,)
    const float* w2     = (const float*)d_in[5];   // (256,128)
    const float* b2     = (const float*)d_in[6];   // (256,)
    const float* bias2  = (const float*)d_in[7];   // (256,)
    const float* w3     = (const float*)d_in[8];   // (128,256)
    const float* b3     = (const float*)d_in[9];   // (128,)
    const float* bias3  = (const float*)d_in[10];  // (128,)
    float* out = (float*)d_out;

    const int E = in_sizes[1];
    const int N = out_size / D1;
    const int* row = ei;
    const int* col = ei + E;

    const int NBLK = (E + EPB - 1) / EPB;          // edge blocks (391 @ E=1.6M)
    const int NBUK = (N + NPB - 1) >> BSH;         // node buckets (391 @ N=100K)
    const int NT   = NBUK * NBLK;

    // workspace layout
    float* dinv    = (float*)d_ws;                                   // N
    float* pv_self = dinv + N;                                       // N
    float* x1      = pv_self + N;                                    // N
    int*   col_ptr = (int*)(x1 + N);                                 // N+8
    int*   partials= col_ptr + N + 8;                                // 1024
    int2*  srt_rp  = (int2*)(partials + 1024);                       // E int2
    unsigned int* p2b = (unsigned int*)(srt_rp + (size_t)E);         // N*64 uints (bf16 p2)
    int*   TS      = (int*)(p2b + (size_t)N * 64);                   // 2*NT scanned table
    int*   T       = TS + (size_t)2 * NT;                            // 2*NT raw histograms
    int2*  Y       = (int2*)(T + (size_t)2 * NT);                    // E (row-bucketed edges)
    unsigned short* w2f = (unsigned short*)(Y + (size_t)E);          // 32768 bf16 (frag layout)
    unsigned short* w3f = w2f + 32768;                               // 32768 bf16 (frag layout)
    unsigned short* zb  = w3f + 32768;                               // N*128 bf16 z (de-aliased)
    // alias:
    int2* X = (int2*)p2b;                    // E entries; dead before k_prop2b writes p2b (E*8 <= N*256)

    const int B = 256;
    const int n2 = 2 * NT;
    const int scan_blocks = (n2 + 2047) / 2048;    // 150 @ default sizes (<= 1024)

    // bucket-sort pipeline: LDS atomics only, zero global atomics, no memsets
    k_hist<<<NBLK, 1024, 0, stream>>>(row, col, T, E, NBLK, NBUK);
    k_scan_local<<<scan_blocks, 256, 0, stream>>>(T, TS, partials, n2);
    k_scan_cvt<<<33, 1024, 0, stream>>>(partials, scan_blocks, w2, w3, w2f, w3f);
    k_scat<<<NBLK, 1024, 0, stream>>>(row, col, val, TS, partials, X, Y, E, NBLK, NBUK);
    k_rowstats<<<NBUK, 512, 0, stream>>>(Y, TS, partials, dinv, pv_self, N, E, NBLK, NBUK);
    k_colfinal<<<NBUK, 512, 0, stream>>>(X, TS, partials, dinv, pv_self, col_ptr, srt_rp, x1, N, E, NBLK, NBUK);

    // conv2 propagate -> bf16 p2, then fused MFMA chain p2 -> H(LDS) -> z
    k_prop2b<<<(N + 3) / 4, 256, 0, stream>>>(col_ptr, srt_rp, pv_self, x1, w1, b1, p2b, N);
    k_gemm_fused4<<<(N + 63) / 64, 256, 0, stream>>>(p2b, w2f, b2, bias2, w3f, b3, x1, zb, N);

    // conv3 gather propagate + fused bias3/leaky
    k_prop3_bf16<<<(N + 3) / 4, 256, 0, stream>>>(col_ptr, srt_rp, pv_self, (const unsigned int*)zb, bias3, out, N);
}